// Round 1
// 3713.866 us; speedup vs baseline: 2.6374x; 2.6374x over previous
//
#include <hip/hip_runtime.h>
#include <math.h>

typedef __bf16 bf16;
typedef bf16 bf16x8 __attribute__((ext_vector_type(8)));
typedef float floatx4 __attribute__((ext_vector_type(4)));
typedef unsigned int u32;
typedef unsigned short u16;
typedef unsigned long long u64;

// ---- dtype-polymorphic loads (inputs may be bf16 or f32; decided on-device) ----
template<bool F32>
__device__ __forceinline__ float loadS(const void* p, long long i) {
  if constexpr (F32) return ((const float*)p)[i];
  else               return (float)((const bf16*)p)[i];
}
template<bool F32>
__device__ __forceinline__ bf16x8 load8(const void* p, long long i) {
  if constexpr (F32) {
    const float* f = (const float*)p + i;
    float4 a = *(const float4*)f;
    float4 b = *(const float4*)(f + 4);
    bf16x8 r;
    r[0]=(bf16)a.x; r[1]=(bf16)a.y; r[2]=(bf16)a.z; r[3]=(bf16)a.w;
    r[4]=(bf16)b.x; r[5]=(bf16)b.y; r[6]=(bf16)b.z; r[7]=(bf16)b.w;
    return r;
  } else {
    return *(const bf16x8*)((const bf16*)p + i);
  }
}

// ---- dtype sniffer: low u16 of each word is a bf16 value (exp in [0x70,0x80])
// ---- for bf16 data, or uniform f32 mantissa bits (~93% outliers) for f32 data.
__global__ void sniff_k(const u32* __restrict__ w, u32* __restrict__ dflag) {
  int out = 0;
  for (int i = 0; i < 256; ++i) {
    u32 e = (w[i] >> 7) & 0xFF;
    out += (e < 0x70 || e > 0x80) ? 1 : 0;
  }
  *dflag = (out > 64) ? 1u : 0u;   // 1 = inputs are f32
}

// ---------------------------------------------------------------------------
// Generic MFMA GEMM: C[M,N] = act(alpha * A[M,K] @ B + bias)
// Guarded by dtype flag (want==2 -> always run).  Internal tensors are bf16.
// ---------------------------------------------------------------------------
template<bool AF32, bool BF32, bool GATHER, bool SPLITA, bool BTMODE,
         bool HASBIAS, int ACT, bool OUTF32, bool CAUSAL>
__global__ __launch_bounds__(256)
void gemm_k(const u32* __restrict__ gflag, u32 want,
            const void* __restrict__ A, const void* __restrict__ A2,
            const int* __restrict__ idx,
            const void* __restrict__ B, const void* __restrict__ bias,
            void* __restrict__ Cout,
            int K, int N, int lda, int ldb,
            long long sAb, long long sBb, long long sCb, float alpha)
{
  if (want != 2u && *gflag != want) return;
  const int m0 = blockIdx.y * 128;
  const int n0 = blockIdx.x * 128;
  if (CAUSAL && n0 > m0) return;
  const int z = blockIdx.z;

  __shared__ bf16 lA[128][40];   // +8 pad; 80B row stride (16B-multiple)
  __shared__ bf16 lB[128][40];

  const int tid = threadIdx.x;
  const int wave = tid >> 6, lane = tid & 63;
  const int wx = wave & 1, wy = wave >> 1;
  const int lm = lane & 15, lq = lane >> 4;

  floatx4 acc[4][4];
  const floatx4 zero4 = {0.f, 0.f, 0.f, 0.f};
#pragma unroll
  for (int i = 0; i < 4; ++i)
#pragma unroll
    for (int j = 0; j < 4; ++j) acc[i][j] = zero4;

  for (int k0 = 0; k0 < K; k0 += 32) {
    // ---- stage A tile (128 x 32) ----
#pragma unroll
    for (int i = 0; i < 2; ++i) {
      int c = i * 256 + tid;
      int row = c >> 2, kg = (c & 3) * 8;
      long long rg = m0 + row;
      bf16x8 av;
      if constexpr (GATHER) {
        av = load8<AF32>(A, (long long)idx[rg] * lda + (k0 + kg));
      } else if constexpr (SPLITA) {
        long long ka = k0 + kg;
        if (ka < 1024) av = load8<AF32>(A,  rg * (long long)lda + ka);
        else           av = load8<AF32>(A2, rg * (long long)lda + (ka - 1024));
      } else {
        av = load8<AF32>(A, (long long)z * sAb + rg * (long long)lda + (k0 + kg));
      }
      *(bf16x8*)(&lA[row][kg]) = av;
    }
    // ---- stage B tile ----
    if constexpr (BTMODE) {
#pragma unroll
      for (int i = 0; i < 2; ++i) {
        int c = i * 256 + tid;
        int row = c >> 2, kg = (c & 3) * 8;
        *(bf16x8*)(&lB[row][kg]) =
            load8<BF32>(B, (long long)z * sBb + (long long)(n0 + row) * ldb + (k0 + kg));
      }
    } else {
#pragma unroll
      for (int i = 0; i < 2; ++i) {
        int c = i * 256 + tid;
        int col = c & 127, kg = (c >> 7) * 8;
        bf16x8 tv;
#pragma unroll
        for (int j = 0; j < 8; ++j)
          tv[j] = (bf16)loadS<BF32>(B, (long long)z * sBb +
                                       (long long)(k0 + kg + j) * ldb + (n0 + col));
        *(bf16x8*)(&lB[col][kg]) = tv;
      }
    }
    __syncthreads();
    bf16x8 af[4], bfr[4];
#pragma unroll
    for (int i = 0; i < 4; ++i)
      af[i] = *(const bf16x8*)(&lA[wy * 64 + i * 16 + lm][lq * 8]);
#pragma unroll
    for (int j = 0; j < 4; ++j)
      bfr[j] = *(const bf16x8*)(&lB[wx * 64 + j * 16 + lm][lq * 8]);
#pragma unroll
    for (int i = 0; i < 4; ++i)
#pragma unroll
      for (int j = 0; j < 4; ++j)
        acc[i][j] = __builtin_amdgcn_mfma_f32_16x16x32_bf16(af[i], bfr[j], acc[i][j], 0, 0, 0);
    __syncthreads();
  }

  // ---- epilogue: C/D layout col=lane&15, row=(lane>>4)*4+r ----
#pragma unroll
  for (int i = 0; i < 4; ++i) {
    int row = m0 + wy * 64 + i * 16 + lq * 4;
#pragma unroll
    for (int j = 0; j < 4; ++j) {
      int col = n0 + wx * 64 + j * 16 + lm;
      float bv = 0.f;
      if constexpr (HASBIAS) bv = loadS<BF32>(bias, col);
#pragma unroll
      for (int r = 0; r < 4; ++r) {
        float v = acc[i][j][r] * alpha + bv;
        if constexpr (ACT == 1) v = tanhf(v);
        long long off = (long long)z * sCb + (long long)(row + r) * N + col;
        if constexpr (OUTF32) ((float*)Cout)[off] = v;
        else                  ((bf16*)Cout)[off] = (bf16)v;
      }
    }
  }
}

// ---------------------------------------------------------------------------
// RNN scan: h_t = tanh(pre_t + h_{t-1} @ w_hh)
// 64 persistent blocks, each owns 16 output cols.
// Sync: self-synchronizing tagged records. Each u64 record = (h-pair << 32) |
// step-tag, stored/loaded with RELAXED agent-scope atomics (sc0+sc1 -> LLC,
// coherent across XCDs). Tag+payload travel in one atomic word, so there are
// NO fences and NO separate flag round trip. Records double-buffered by step
// parity: a producer can only overwrite a buffer 2 steps later, which the tag
// protocol proves happens only after every consumer has read it.
// Compute: K=1024 split across all 4 waves (K=256 each), LDS reduction.
// ---------------------------------------------------------------------------
template<bool WF32>
__global__ __launch_bounds__(256)
void rnn_k(const u32* __restrict__ gflag, u32 want,
           const void* __restrict__ w_hh, const bf16* __restrict__ pre,
           bf16* __restrict__ hs, u64* __restrict__ recs)
{
  if (*gflag != want) return;
  __shared__ bf16 WT[16][1032];
  __shared__ bf16 hl[4][1032];
  __shared__ float red[4][16][4];   // [wave][col][batch]
  const int tid = threadIdx.x;
  const int blk = blockIdx.x;
  const int n0 = blk * 16;
  const int wave = tid >> 6, lane = tid & 63;
  const int lm = lane & 15, lq = lane >> 4;

  // one-time: stage transposed w_hh columns n0..n0+15
  for (int i = tid; i < 16 * 1024; i += 256) {
    int c = i & 15, k = i >> 4;
    WT[c][k] = (bf16)loadS<WF32>(w_hh, (long long)k * 1024 + n0 + c);
  }
  __syncthreads();

  // each thread polls 8 of the 2048 records; record r: b = r>>9, pair = r&511
  const int rbase = tid * 8;

  for (int t = 0; t < 1024; ++t) {
    // prefetch pre (independent of h) so its latency overlaps the poll
    float prev = 0.f;
    if (wave == 0)
      prev = (float)pre[((long long)((lane >> 4) * 1024 + t)) * 1024 + n0 + (lane & 15)];

    // ---- poll h_{t-1}: records tagged t live in buffer (t+1)&1 ----
    const u64* rb = recs + (((t + 1) & 1) << 11);
    const u32 want_tag = (u32)t;
    u64 v[8];
#pragma unroll
    for (int i = 0; i < 8; ++i)
      v[i] = __hip_atomic_load(rb + rbase + i, __ATOMIC_RELAXED, __HIP_MEMORY_SCOPE_AGENT);
    for (;;) {
      bool ok = true;
#pragma unroll
      for (int i = 0; i < 8; ++i) ok &= ((u32)v[i] == want_tag);
      if (ok) break;
      __builtin_amdgcn_s_sleep(1);
#pragma unroll
      for (int i = 0; i < 8; ++i)
        if ((u32)v[i] != want_tag)
          v[i] = __hip_atomic_load(rb + rbase + i, __ATOMIC_RELAXED, __HIP_MEMORY_SCOPE_AGENT);
    }
#pragma unroll
    for (int i = 0; i < 8; ++i) {
      int r = rbase + i;
      *((u32*)&hl[r >> 9][0] + (r & 511)) = (u32)(v[i] >> 32);
    }
    __syncthreads();

    // ---- matmul: wave w covers K in [w*256, w*256+256) ----
    {
      const int k0w = wave << 8;
      floatx4 acc0 = {0.f,0.f,0.f,0.f}, acc1 = {0.f,0.f,0.f,0.f};
#pragma unroll
      for (int kk = 0; kk < 256; kk += 64) {
        int k0 = k0w + kk;
        bf16x8 a0 = *(const bf16x8*)(&hl[lm & 3][k0 + lq * 8]);
        bf16x8 b0 = *(const bf16x8*)(&WT[lm][k0 + lq * 8]);
        acc0 = __builtin_amdgcn_mfma_f32_16x16x32_bf16(a0, b0, acc0, 0, 0, 0);
        bf16x8 a1 = *(const bf16x8*)(&hl[lm & 3][k0 + 32 + lq * 8]);
        bf16x8 b1 = *(const bf16x8*)(&WT[lm][k0 + 32 + lq * 8]);
        acc1 = __builtin_amdgcn_mfma_f32_16x16x32_bf16(a1, b1, acc1, 0, 0, 0);
      }
      // D layout: rows 0..3 (= batches) live at lq==0, col = lm
      if (lq == 0) {
#pragma unroll
        for (int r = 0; r < 4; ++r) red[wave][lm][r] = acc0[r] + acc1[r];
      }
    }
    __syncthreads();

    // ---- epilogue on wave 0: lane = b*16 + col (64 values = 64 lanes) ----
    if (wave == 0) {
      const int col = lane & 15, b = lane >> 4;
      float s = red[0][col][b] + red[1][col][b] + red[2][col][b] + red[3][col][b] + prev;
      float hv = tanhf(s);
      u16 bits = __builtin_bit_cast(u16, (bf16)hv);
      u16 other = (u16)__shfl_xor((int)bits, 1, 64);
      if ((col & 1) == 0) {
        u32 pairv = (u32)bits | ((u32)other << 16);
        int pidx = (b << 9) + ((n0 + col) >> 1);
        u64 rec = ((u64)pairv << 32) | (u32)(t + 1);
        __hip_atomic_store(recs + ((t & 1) << 11) + pidx, rec,
                           __ATOMIC_RELAXED, __HIP_MEMORY_SCOPE_AGENT);
        long long off = (((long long)(b * 1024 + t)) * 1024 + n0 + col) >> 1;
        ((u32*)hs)[off] = pairv;
      }
    }
    __syncthreads();   // protect hl/red reuse next step
  }
}

// ---------------------------------------------------------------------------
// Causal softmax; writes P (bf16) with zeros past the diagonal.
// ---------------------------------------------------------------------------
__global__ __launch_bounds__(256)
void softmax_k(const float* __restrict__ S, bf16* __restrict__ P)
{
  long long r = blockIdx.x;
  int t = (int)(r & 1023);
  const float* row = S + r * 1024;
  bf16* prow = P + r * 1024;
  const int tid = threadIdx.x;
  const int wave = tid >> 6, lane = tid & 63;
  __shared__ float rbuf[4];

  float mx = -3.0e38f;
  for (int s = tid; s <= t; s += 256) mx = fmaxf(mx, row[s]);
#pragma unroll
  for (int m = 32; m; m >>= 1) mx = fmaxf(mx, __shfl_xor(mx, m, 64));
  if (lane == 0) rbuf[wave] = mx;
  __syncthreads();
  mx = fmaxf(fmaxf(rbuf[0], rbuf[1]), fmaxf(rbuf[2], rbuf[3]));
  __syncthreads();

  float sm = 0.f;
  for (int s = tid; s <= t; s += 256) sm += expf(row[s] - mx);
#pragma unroll
  for (int m = 32; m; m >>= 1) sm += __shfl_xor(sm, m, 64);
  if (lane == 0) rbuf[wave] = sm;
  __syncthreads();
  sm = rbuf[0] + rbuf[1] + rbuf[2] + rbuf[3];
  float inv = 1.f / sm;

  for (int s = tid; s < 1024; s += 256) {
    float pv = (s <= t) ? expf(row[s] - mx) * inv : 0.f;
    prow[s] = (bf16)pv;
  }
}

// ---------------------------------------------------------------------------
extern "C" void kernel_launch(void* const* d_in, const int* in_sizes, int n_in,
                              void* d_out, int out_size, void* d_ws, size_t ws_size,
                              hipStream_t stream)
{
  const int*  x      = (const int*)d_in[0];
  const void* emb    = d_in[1];
  const void* w_ih   = d_in[2];
  const void* b_ih   = d_in[3];
  const void* w_hh   = d_in[4];
  const void* wq     = d_in[5];
  const void* wk     = d_in[6];
  const void* wv     = d_in[7];
  const void* w_mix  = d_in[8];
  const void* b_mix  = d_in[9];
  const void* w_proj = d_in[10];
  const void* b_proj = d_in[11];

  // d_ws: dflag + hs + h2 (16.03 MB); record buffers live in d_out (see below)
  char* ws = (char*)d_ws;
  u32*  dflag = (u32*)ws;                       // 4B
  bf16* hs    = (bf16*)(ws + 32768);            // 8MB
  bf16* h2    = hs + 4194304;                   // 8MB

  // short-lived tensors live inside d_out (dead before final proj overwrites it)
  char* ob = (char*)d_out;
  bf16* pre = (bf16*)(ob);                      // 8MB
  bf16* q   = (bf16*)(ob + (8u << 20));
  bf16* k_  = (bf16*)(ob + (16u << 20));
  bf16* v   = (bf16*)(ob + (24u << 20));
  float* sc = (float*)(ob + (32u << 20));       // 16MB f32, ends at 48MB
  u64*  recs = (u64*)(ob + (48u << 20));        // 2 x 2048 x 8B = 32KB tagged records
  bf16* P   = q;                                // q dead after scores
  bf16* ctx = k_;                               // k dead after scores

  const long long TH = 1024LL * 1024, TT = 1024LL * 1024;

  hipMemsetAsync(d_ws, 0, 32768, stream);
  hipMemsetAsync(recs, 0, 32768, stream);       // tag 0 == initial h state (zeros)
  sniff_k<<<1, 1, 0, stream>>>((const u32*)emb, dflag);

  // pre = emb[x] @ w_ih + b_ih
  gemm_k<false,false,true,false,false,true,0,false,false><<<dim3(8,32,1),256,0,stream>>>(
      dflag, 0u, emb, nullptr, x, w_ih, b_ih, pre, 512, 1024, 512, 1024, 0, 0, 0, 1.f);
  gemm_k<true, true, true,false,false,true,0,false,false><<<dim3(8,32,1),256,0,stream>>>(
      dflag, 1u, emb, nullptr, x, w_ih, b_ih, pre, 512, 1024, 512, 1024, 0, 0, 0, 1.f);
  // RNN scan -> hs
  rnn_k<false><<<dim3(64),256,0,stream>>>(dflag, 0u, w_hh, pre, hs, recs);
  rnn_k<true ><<<dim3(64),256,0,stream>>>(dflag, 1u, w_hh, pre, hs, recs);
  // q, k, v
  gemm_k<false,false,false,false,false,false,0,false,false><<<dim3(8,32,1),256,0,stream>>>(
      dflag, 0u, hs, nullptr, nullptr, wq, nullptr, q, 1024, 1024, 1024, 1024, 0, 0, 0, 1.f);
  gemm_k<false,true, false,false,false,false,0,false,false><<<dim3(8,32,1),256,0,stream>>>(
      dflag, 1u, hs, nullptr, nullptr, wq, nullptr, q, 1024, 1024, 1024, 1024, 0, 0, 0, 1.f);
  gemm_k<false,false,false,false,false,false,0,false,false><<<dim3(8,32,1),256,0,stream>>>(
      dflag, 0u, hs, nullptr, nullptr, wk, nullptr, k_, 1024, 1024, 1024, 1024, 0, 0, 0, 1.f);
  gemm_k<false,true, false,false,false,false,0,false,false><<<dim3(8,32,1),256,0,stream>>>(
      dflag, 1u, hs, nullptr, nullptr, wk, nullptr, k_, 1024, 1024, 1024, 1024, 0, 0, 0, 1.f);
  gemm_k<false,false,false,false,false,false,0,false,false><<<dim3(8,32,1),256,0,stream>>>(
      dflag, 0u, hs, nullptr, nullptr, wv, nullptr, v, 1024, 1024, 1024, 1024, 0, 0, 0, 1.f);
  gemm_k<false,true, false,false,false,false,0,false,false><<<dim3(8,32,1),256,0,stream>>>(
      dflag, 1u, hs, nullptr, nullptr, wv, nullptr, v, 1024, 1024, 1024, 1024, 0, 0, 0, 1.f);
  // scores = q @ k^T / 32  (shared: all-internal bf16)
  gemm_k<false,false,false,false,true,false,0,true,true><<<dim3(8,8,4),256,0,stream>>>(
      dflag, 2u, q, nullptr, nullptr, k_, nullptr, sc, 1024, 1024, 1024, 1024, TH, TH, TT, 0.03125f);
  softmax_k<<<dim3(4096),256,0,stream>>>(sc, P);
  // ctx = P @ v  (shared)
  gemm_k<false,false,false,false,false,false,0,false,false><<<dim3(8,8,4),256,0,stream>>>(
      dflag, 2u, P, nullptr, nullptr, v, nullptr, ctx, 1024, 1024, 1024, 1024, TT, TH, TH, 1.f);
  // h2 = tanh([hs|ctx] @ w_mix + b_mix)
  gemm_k<false,false,false,true,false,true,1,false,false><<<dim3(8,32,1),256,0,stream>>>(
      dflag, 0u, hs, ctx, nullptr, w_mix, b_mix, h2, 2048, 1024, 1024, 1024, 0, 0, 0, 1.f);
  gemm_k<false,true, false,true,false,true,1,false,false><<<dim3(8,32,1),256,0,stream>>>(
      dflag, 1u, hs, ctx, nullptr, w_mix, b_mix, h2, 2048, 1024, 1024, 1024, 0, 0, 0, 1.f);
  // out = h2 @ w_proj + b_proj   (output dtype follows input dtype)
  gemm_k<false,false,false,false,false,true,0,false,false><<<dim3(250,32,1),256,0,stream>>>(
      dflag, 0u, h2, nullptr, nullptr, w_proj, b_proj, d_out, 1024, 32000, 1024, 32000, 0, 0, 0, 1.f);
  gemm_k<false,true, false,false,false,true,0,true, false><<<dim3(250,32,1),256,0,stream>>>(
      dflag, 1u, h2, nullptr, nullptr, w_proj, b_proj, d_out, 1024, 32000, 1024, 32000, 0, 0, 0, 1.f);
}